// Round 15
// baseline (762.302 us; speedup 1.0000x reference)
//
#include <hip/hip_runtime.h>

// ODE-RNN via MFMA. Two 4-wave blocks per CU: the unified VGPR+AGPR footprint
// (~216/wave) caps occupancy at 2 waves/SIMD = 8 waves/CU (r14's finding);
// an 8-wave block therefore monopolizes the CU. Splitting into 4-wave blocks
// puts TWO independent barrier domains in the same 8-wave budget -> each
// block's compute overlaps the other's phase-latency stalls.
// r8 body (numerically proven) + __launch_bounds__(256,1) so the allocator
// is NOT capped at 128 regs (r8's spill failure) + deferred out_ys (r11).
// 512 blocks x 256 threads (4 waves); NT=4 trajs/block.
// Each wave w: W1 tiles {w, w+4} of f1/z1/r1/h1 + tile w of all four W2
// matrices (44 frags = 176 regs). All phases on all waves; GRU state in-wave.
// Fragment mapping (16x16x32 bf16): A: lane l -> A[l&15][kt*32+(l>>4)*8+j],
// B: lane l -> B[kt*32+(l>>4)*8+j][l&15], C/D: col=l&15, row=(l>>4)*4+reg.

#define NBT   2048
#define TSTEP 200
#define NT    4

typedef short s8v __attribute__((ext_vector_type(8)));   // 8 bf16 (4 VGPRs)
typedef float f4v __attribute__((ext_vector_type(4)));

// LDS: bf16 tiles, row pitch with (pitch/4)%32==4 -> 2-way worst (free)
#define RB_Y 144   // y  [16][64]  bf16 (+pad)
#define RB_C 272   // c  [16][128] bf16 (+pad); also pitch for h buffers
#define OFF_Y  0
#define OFF_C  2304
#define OFF_HF 6656
#define OFF_HZ 11008
#define OFF_HR 15360
#define OFF_HH 19712
#define SMEM_TOT 24064

__device__ __forceinline__ unsigned cvtpk(float lo, float hi) {
    unsigned r;
    asm("v_cvt_pk_bf16_f32 %0, %1, %2" : "=v"(r) : "v"(lo), "v"(hi));
    return r;
}
__device__ __forceinline__ unsigned short f2bf(float f) {
    unsigned int b = __float_as_uint(f);
    return (unsigned short)((b + 0x7fffu + ((b >> 16) & 1u)) >> 16);
}
__device__ __forceinline__ float tanh_f(float x) {
    float e = __expf(2.0f * x);
    return fmaf(-2.0f, __builtin_amdgcn_rcpf(e + 1.0f), 1.0f);
}
__device__ __forceinline__ float sigm_f(float x) {
    return __builtin_amdgcn_rcpf(1.0f + __expf(-x));
}
__device__ __forceinline__ f4v mfma16(s8v a, s8v b, f4v c) {
    return __builtin_amdgcn_mfma_f32_16x16x32_bf16(a, b, c, 0, 0, 0);
}
__device__ __forceinline__ f4v splat(float b) { f4v v = {b, b, b, b}; return v; }

// B-fragment: lane holds W[k0+j][n] j=0..7, bf16 (zero-padded outside)
__device__ __forceinline__ s8v load_bfrag(const float* __restrict__ W,
                                          int Ncols, int Krows, int k0, int n) {
    s8v r;
#pragma unroll
    for (int j = 0; j < 8; ++j) {
        const int k = k0 + j;
        const float v = (k < Krows && n < Ncols) ? W[k * Ncols + n] : 0.0f;
        r[j] = (short)f2bf(v);
    }
    return r;
}

// A-fragment: lane l -> act[l&15][kt*32+(l>>4)*8 .. +7]
template <int RB>
__device__ __forceinline__ s8v load_af(const char* base, int lane, int kt) {
    return *(const s8v*)(base + (lane & 15) * RB + ((lane >> 4) * 16) + kt * 64);
}

// write 4 fp32 values (rows rb..rb+3, one col) as bf16 via cvt_pk
__device__ __forceinline__ void store4(char* base, int col2, int rb, int pitch,
                                       float v0, float v1, float v2, float v3) {
    const unsigned u01 = cvtpk(v0, v1), u23 = cvtpk(v2, v3);
    *(short*)(base + (rb + 0) * pitch + col2) = (short)(u01 & 0xffffu);
    *(short*)(base + (rb + 1) * pitch + col2) = (short)(u01 >> 16);
    *(short*)(base + (rb + 2) * pitch + col2) = (short)(u23 & 0xffffu);
    *(short*)(base + (rb + 3) * pitch + col2) = (short)(u23 >> 16);
}
__device__ __forceinline__ void store_tanh(char* base, int n0, int lane, f4v a) {
    store4(base, (n0 + (lane & 15)) * 2, (lane >> 4) * 4, RB_C,
           tanh_f(a[0]), tanh_f(a[1]), tanh_f(a[2]), tanh_f(a[3]));
}

__global__ __launch_bounds__(256, 1) void ode_rnn_r15(
    const float* __restrict__ data, const float* __restrict__ tsv,
    const float* __restrict__ Wf1, const float* __restrict__ bf1,
    const float* __restrict__ Wf2, const float* __restrict__ bf2,
    const float* __restrict__ Wz1, const float* __restrict__ bz1,
    const float* __restrict__ Wz2, const float* __restrict__ bz2,
    const float* __restrict__ Wr1, const float* __restrict__ br1,
    const float* __restrict__ Wr2, const float* __restrict__ br2,
    const float* __restrict__ Wh1, const float* __restrict__ bh1,
    const float* __restrict__ Wh2, const float* __restrict__ bh2,
    float* __restrict__ out_yi, float* __restrict__ out_ys)
{
    __shared__ __align__(16) char smem[SMEM_TOT];

    const int tid  = threadIdx.x;
    const int lane = tid & 63;
    const int wv   = tid >> 6;          // 0..3
    const int b0   = blockIdx.x * NT;

    for (int i = tid; i < SMEM_TOT / 4; i += 256) ((unsigned*)smem)[i] = 0u;

    // ---- stage weight B-fragments ----
    const int kb = (lane >> 4) * 8;
    const int nA = wv * 16 + (lane & 15);          // W1 tile wv
    const int nB = (wv + 4) * 16 + (lane & 15);    // W1 tile wv+4
    const int n2 = wv * 16 + (lane & 15);          // W2 tile wv (cols 0..63)

    s8v Bf1[2][2], Bz1[2][4], Br1[2][4], Bh1[2][4];
    s8v Bf2[4], Bz2[4], Br2[4], Bh2[4];
#pragma unroll
    for (int kt = 0; kt < 2; ++kt) {
        Bf1[0][kt] = load_bfrag(Wf1, 100, 64, kt * 32 + kb, nA);
        Bf1[1][kt] = load_bfrag(Wf1, 100, 64, kt * 32 + kb, nB);
    }
#pragma unroll
    for (int kt = 0; kt < 4; ++kt) {
        Bz1[0][kt] = load_bfrag(Wz1, 100, 128, kt * 32 + kb, nA);
        Bz1[1][kt] = load_bfrag(Wz1, 100, 128, kt * 32 + kb, nB);
        Br1[0][kt] = load_bfrag(Wr1, 100, 128, kt * 32 + kb, nA);
        Br1[1][kt] = load_bfrag(Wr1, 100, 128, kt * 32 + kb, nB);
        Bh1[0][kt] = load_bfrag(Wh1, 100, 128, kt * 32 + kb, nA);
        Bh1[1][kt] = load_bfrag(Wh1, 100, 128, kt * 32 + kb, nB);
        Bf2[kt] = load_bfrag(Wf2, 64, 100, kt * 32 + kb, n2);
        Bz2[kt] = load_bfrag(Wz2, 64, 100, kt * 32 + kb, n2);
        Br2[kt] = load_bfrag(Wr2, 64, 100, kt * 32 + kb, n2);
        Bh2[kt] = load_bfrag(Wh2, 64, 100, kt * 32 + kb, n2);
    }

    const float b1fA = (nA < 100) ? bf1[nA] : 0.0f;
    const float b1fB = (nB < 100) ? bf1[nB] : 0.0f;
    const float b1zA = (nA < 100) ? bz1[nA] : 0.0f;
    const float b1zB = (nB < 100) ? bz1[nB] : 0.0f;
    const float b1rA = (nA < 100) ? br1[nA] : 0.0f;
    const float b1rB = (nB < 100) ? br1[nB] : 0.0f;
    const float b1hA = (nA < 100) ? bh1[nA] : 0.0f;
    const float b1hB = (nB < 100) ? bh1[nB] : 0.0f;
    const float bF2 = bf2[n2], bZ2 = bz2[n2], bR2 = br2[n2], bH2 = bh2[n2];

    // x staging: thread t -> traj t>>6 (0..3), elem t&63 (scalar)
    const int xtr = tid >> 6;
    const int xd  = tid & 63;

    const int col2 = n2 * 2;
    const int rb   = (lane >> 4) * 4;

    f4v y_reg = splat(0.0f), yode = splat(0.0f), zf = splat(0.0f);
    float dt = tsv[1] - tsv[0];
    __syncthreads();

    for (int s = 0; s < TSTEP - 1; ++s) {
        // deferred out_ys store for step s-1 (write-ack drains under P1)
        if (s > 0 && lane < 16) {
#pragma unroll
            for (int r = 0; r < 4; ++r)
                out_ys[((size_t)(b0 + r) * (TSTEP - 1) + (s - 1)) * 64 + n2] =
                    y_reg[r];
        }
        const float xv = data[((size_t)(b0 + xtr) * TSTEP + (s + 1)) * 64 + xd];

        // ---- P1: f1 hidden, tiles wv & wv+4 ----
        {
            const s8v ya0 = load_af<RB_Y>(smem + OFF_Y, lane, 0);
            const s8v ya1 = load_af<RB_Y>(smem + OFF_Y, lane, 1);
            f4v aA = splat(b1fA), aB = splat(b1fB);
            aA = mfma16(ya0, Bf1[0][0], aA); aA = mfma16(ya1, Bf1[0][1], aA);
            aB = mfma16(ya0, Bf1[1][0], aB); aB = mfma16(ya1, Bf1[1][1], aB);
            store_tanh(smem + OFF_HF, wv * 16, lane, aA);
            store_tanh(smem + OFF_HF, (wv + 4) * 16, lane, aB);
        }
        __syncthreads();

        // ---- P2: f2 out (tile wv) -> yode -> c[:, :64]; x -> c[:, 64:] ----
        {
            f4v ac = splat(bF2);
#pragma unroll
            for (int kt = 0; kt < 4; ++kt)
                ac = mfma16(load_af<RB_C>(smem + OFF_HF, lane, kt), Bf2[kt], ac);
#pragma unroll
            for (int r = 0; r < 4; ++r) yode[r] = fmaf(dt, ac[r], y_reg[r]);
            store4(smem + OFF_C, col2, rb, RB_C, yode[0], yode[1], yode[2], yode[3]);
            *(unsigned short*)(smem + OFF_C + xtr * RB_C + 128 + xd * 2) = f2bf(xv);
        }
        __syncthreads();

        // ---- P3: z1 + r1 hidden, tiles wv & wv+4 (4 indep chains) ----
        {
            const s8v c0 = load_af<RB_C>(smem + OFF_C, lane, 0);
            const s8v c1 = load_af<RB_C>(smem + OFF_C, lane, 1);
            const s8v c2 = load_af<RB_C>(smem + OFF_C, lane, 2);
            const s8v c3 = load_af<RB_C>(smem + OFF_C, lane, 3);
            f4v azA = splat(b1zA), azB = splat(b1zB);
            f4v arA = splat(b1rA), arB = splat(b1rB);
            azA = mfma16(c0, Bz1[0][0], azA); azA = mfma16(c1, Bz1[0][1], azA);
            azA = mfma16(c2, Bz1[0][2], azA); azA = mfma16(c3, Bz1[0][3], azA);
            azB = mfma16(c0, Bz1[1][0], azB); azB = mfma16(c1, Bz1[1][1], azB);
            azB = mfma16(c2, Bz1[1][2], azB); azB = mfma16(c3, Bz1[1][3], azB);
            arA = mfma16(c0, Br1[0][0], arA); arA = mfma16(c1, Br1[0][1], arA);
            arA = mfma16(c2, Br1[0][2], arA); arA = mfma16(c3, Br1[0][3], arA);
            arB = mfma16(c0, Br1[1][0], arB); arB = mfma16(c1, Br1[1][1], arB);
            arB = mfma16(c2, Br1[1][2], arB); arB = mfma16(c3, Br1[1][3], arB);
            store_tanh(smem + OFF_HZ, wv * 16, lane, azA);
            store_tanh(smem + OFF_HZ, (wv + 4) * 16, lane, azB);
            store_tanh(smem + OFF_HR, wv * 16, lane, arA);
            store_tanh(smem + OFF_HR, (wv + 4) * 16, lane, arB);
        }
        __syncthreads();

        // ---- P4: z2 + r2 out (tile wv, 2 indep chains); zf regs; ch -> c ----
        {
            f4v az = splat(bZ2), ar = splat(bR2);
#pragma unroll
            for (int kt = 0; kt < 4; ++kt) {
                az = mfma16(load_af<RB_C>(smem + OFF_HZ, lane, kt), Bz2[kt], az);
                ar = mfma16(load_af<RB_C>(smem + OFF_HR, lane, kt), Br2[kt], ar);
            }
            float ch[4];
#pragma unroll
            for (int r = 0; r < 4; ++r) {
                zf[r] = sigm_f(az[r]);
                ch[r] = yode[r] * sigm_f(ar[r]);
            }
            store4(smem + OFF_C, col2, rb, RB_C, ch[0], ch[1], ch[2], ch[3]);
        }
        __syncthreads();

        // ---- P5: h1 hidden, tiles wv & wv+4 ----
        {
            const s8v d0 = load_af<RB_C>(smem + OFF_C, lane, 0);
            const s8v d1 = load_af<RB_C>(smem + OFF_C, lane, 1);
            const s8v d2 = load_af<RB_C>(smem + OFF_C, lane, 2);
            const s8v d3 = load_af<RB_C>(smem + OFF_C, lane, 3);
            f4v ahA = splat(b1hA), ahB = splat(b1hB);
            ahA = mfma16(d0, Bh1[0][0], ahA); ahA = mfma16(d1, Bh1[0][1], ahA);
            ahA = mfma16(d2, Bh1[0][2], ahA); ahA = mfma16(d3, Bh1[0][3], ahA);
            ahB = mfma16(d0, Bh1[1][0], ahB); ahB = mfma16(d1, Bh1[1][1], ahB);
            ahB = mfma16(d2, Bh1[1][2], ahB); ahB = mfma16(d3, Bh1[1][3], ahB);
            store_tanh(smem + OFF_HH, wv * 16, lane, ahA);
            store_tanh(smem + OFF_HH, (wv + 4) * 16, lane, ahB);
        }
        __syncthreads();

        // ---- P6: h2 out (tile wv); y = (1-z)*h + z*yode; y -> LDS ----
        {
            f4v ah = splat(bH2);
#pragma unroll
            for (int kt = 0; kt < 4; ++kt)
                ah = mfma16(load_af<RB_C>(smem + OFF_HH, lane, kt), Bh2[kt], ah);
#pragma unroll
            for (int r = 0; r < 4; ++r) {
                const float h = tanh_f(ah[r]);
                y_reg[r] = (1.0f - zf[r]) * h + zf[r] * yode[r];
            }
            store4(smem + OFF_Y, col2, rb, RB_Y, y_reg[0], y_reg[1], y_reg[2], y_reg[3]);
        }
        dt = tsv[s] - tsv[s + 1];
        __syncthreads();
    }

    // final flush: out_ys step 198 + out_yi
    if (lane < 16) {
#pragma unroll
        for (int r = 0; r < 4; ++r) {
            out_ys[((size_t)(b0 + r) * (TSTEP - 1) + (TSTEP - 2)) * 64 + n2] =
                y_reg[r];
            out_yi[(size_t)(b0 + r) * 64 + n2] = y_reg[r];
        }
    }
}

extern "C" void kernel_launch(void* const* d_in, const int* in_sizes, int n_in,
                              void* d_out, int out_size, void* d_ws, size_t ws_size,
                              hipStream_t stream) {
    const float* data = (const float*)d_in[0];
    const float* tsv  = (const float*)d_in[1];
    const float* Wf1 = (const float*)d_in[2];  const float* bf1 = (const float*)d_in[3];
    const float* Wf2 = (const float*)d_in[4];  const float* bf2 = (const float*)d_in[5];
    const float* Wz1 = (const float*)d_in[6];  const float* bz1 = (const float*)d_in[7];
    const float* Wz2 = (const float*)d_in[8];  const float* bz2 = (const float*)d_in[9];
    const float* Wr1 = (const float*)d_in[10]; const float* br1 = (const float*)d_in[11];
    const float* Wr2 = (const float*)d_in[12]; const float* br2 = (const float*)d_in[13];
    const float* Wh1 = (const float*)d_in[14]; const float* bh1 = (const float*)d_in[15];
    const float* Wh2 = (const float*)d_in[16]; const float* bh2 = (const float*)d_in[17];

    float* out_yi = (float*)d_out;
    float* out_ys = out_yi + (size_t)NBT * 64;

    ode_rnn_r15<<<NBT / NT, 256, 0, stream>>>(
        data, tsv, Wf1, bf1, Wf2, bf2, Wz1, bz1, Wz2, bz2,
        Wr1, br1, Wr2, br2, Wh1, bh1, Wh2, bh2, out_yi, out_ys);
}

// Round 16
// 346.955 us; speedup vs baseline: 2.1971x; 2.1971x over previous
//
#include <hip/hip_runtime.h>

// ODE-RNN via MFMA. r11 (352us best) + ONE change: s_setprio(1/0) around all
// MFMA clusters (T5). r11's waves have role diversity at P2/P4/P6 (isA vs
// isB do different work) -> scheduler can favor MFMA-ready waves. Clean
// single-variable test; everything else verbatim r11.
// 256 blocks x 512 threads (8 waves); NT=8; W in VGPRs as bf16 B-fragments;
// activations bf16 in LDS; GRU state fp32 in regs (waves 0-3);
// x-projection pipelining (r10) + deferred out_ys stores (r11).
// Fragment mapping (16x16x32 bf16): A: lane l -> A[l&15][kt*32+(l>>4)*8+j],
// B: lane l -> B[kt*32+(l>>4)*8+j][l&15], C/D: col=l&15, row=(l>>4)*4+reg.

#define NBT   2048
#define TSTEP 200
#define NT    8

typedef short s8v __attribute__((ext_vector_type(8)));   // 8 bf16 (4 VGPRs)
typedef float f4v __attribute__((ext_vector_type(4)));

// LDS pitches: (pitch/4)%32==4 -> row-base bank 4r mod 32, 16B aligned
#define RB64  144   // 64-col bf16 buffers: y, c(yode/ch), xbuf
#define RB128 272   // 128-col bf16 buffers: h_f/h_z/h_r/h_h (K pad 100->128)
#define OFF_Y  0
#define OFF_C  2304
#define OFF_X  4608
#define OFF_HF 6912
#define OFF_HZ 11264
#define OFF_HR 15616
#define OFF_HH 19968
#define SMEM_TOT 24320

__device__ __forceinline__ unsigned cvtpk(float lo, float hi) {
    unsigned r;
    asm("v_cvt_pk_bf16_f32 %0, %1, %2" : "=v"(r) : "v"(lo), "v"(hi));
    return r;
}
__device__ __forceinline__ unsigned short f2bf(float f) {  // staging only
    unsigned int b = __float_as_uint(f);
    return (unsigned short)((b + 0x7fffu + ((b >> 16) & 1u)) >> 16);
}
__device__ __forceinline__ float bf2f(unsigned short u) {
    return __uint_as_float(((unsigned)u) << 16);
}
__device__ __forceinline__ float tanh_f(float x) {
    float e = __expf(2.0f * x);
    return fmaf(-2.0f, __builtin_amdgcn_rcpf(e + 1.0f), 1.0f);
}
__device__ __forceinline__ float sigm_f(float x) {
    return __builtin_amdgcn_rcpf(1.0f + __expf(-x));
}
__device__ __forceinline__ f4v mfma16(s8v a, s8v b, f4v c) {
    return __builtin_amdgcn_mfma_f32_16x16x32_bf16(a, b, c, 0, 0, 0);
}
__device__ __forceinline__ f4v splat(float b) { f4v v = {b, b, b, b}; return v; }

// B-fragment: lane holds W[k0+j][n] j=0..7, bf16 (zero-padded outside)
__device__ __forceinline__ s8v load_bfrag(const float* __restrict__ W,
                                          int Ncols, int Krows, int k0, int n) {
    s8v r;
#pragma unroll
    for (int j = 0; j < 8; ++j) {
        const int k = k0 + j;
        const float v = (k < Krows && n < Ncols) ? W[k * Ncols + n] : 0.0f;
        r[j] = (short)f2bf(v);
    }
    return r;
}

// A-fragment: lane l -> act[l&15][kt*32+(l>>4)*8 .. +7]; row byte off kt*64+(l>>4)*16
template <int RB>
__device__ __forceinline__ s8v load_af(const char* base, int lane, int kt) {
    return *(const s8v*)(base + (lane & 15) * RB + ((lane >> 4) * 16) + kt * 64);
}

// write 4 fp32 values (rows rb..rb+3, one col) as bf16 via cvt_pk
__device__ __forceinline__ void store4(char* base, int col2, int rb, int pitch,
                                       float v0, float v1, float v2, float v3) {
    const unsigned u01 = cvtpk(v0, v1), u23 = cvtpk(v2, v3);
    *(short*)(base + (rb + 0) * pitch + col2) = (short)(u01 & 0xffffu);
    *(short*)(base + (rb + 1) * pitch + col2) = (short)(u01 >> 16);
    *(short*)(base + (rb + 2) * pitch + col2) = (short)(u23 & 0xffffu);
    *(short*)(base + (rb + 3) * pitch + col2) = (short)(u23 >> 16);
}
__device__ __forceinline__ void store_tanh(char* base, int n0, int lane, f4v a) {
    store4(base, (n0 + (lane & 15)) * 2, (lane >> 4) * 4, RB128,
           tanh_f(a[0]), tanh_f(a[1]), tanh_f(a[2]), tanh_f(a[3]));
}

__global__ __launch_bounds__(512, 2) void ode_rnn_r16(
    const float* __restrict__ data, const float* __restrict__ tsv,
    const float* __restrict__ Wf1, const float* __restrict__ bf1,
    const float* __restrict__ Wf2, const float* __restrict__ bf2,
    const float* __restrict__ Wz1, const float* __restrict__ bz1,
    const float* __restrict__ Wz2, const float* __restrict__ bz2,
    const float* __restrict__ Wr1, const float* __restrict__ br1,
    const float* __restrict__ Wr2, const float* __restrict__ br2,
    const float* __restrict__ Wh1, const float* __restrict__ bh1,
    const float* __restrict__ Wh2, const float* __restrict__ bh2,
    float* __restrict__ out_yi, float* __restrict__ out_ys)
{
    __shared__ __align__(16) char smem[SMEM_TOT];

    const int tid  = threadIdx.x;
    const int lane = tid & 63;
    const int wv   = tid >> 6;          // 0..7
    const bool isA = (wv < 4);          // state-carrying waves
    const int b0   = blockIdx.x * NT;

    for (int i = tid; i < SMEM_TOT / 4; i += 512) ((unsigned*)smem)[i] = 0u;

    // ---- stage weight B-fragments ----
    const int kb = (lane >> 4) * 8;
    const int n1 = wv * 16 + (lane & 15);          // W1 tile wv (cols 0..127)
    const int n2 = (wv & 3) * 16 + (lane & 15);    // W2 tile (cols 0..63)

    // W1 zrh: frags [0..1] = K 0-63 (yode/ch part), [2..3] = K 64-127 (x part)
    s8v Bf1[2], Bz1[4], Br1[4], Bh1[4];
    s8v Bf2[4], Bz2[4], Bh2[4], Br2[4];
#pragma unroll
    for (int kt = 0; kt < 2; ++kt)
        Bf1[kt] = load_bfrag(Wf1, 100, 64, kt * 32 + kb, n1);
#pragma unroll
    for (int kt = 0; kt < 4; ++kt) {
        Bz1[kt] = load_bfrag(Wz1, 100, 128, kt * 32 + kb, n1);
        Br1[kt] = load_bfrag(Wr1, 100, 128, kt * 32 + kb, n1);
        Bh1[kt] = load_bfrag(Wh1, 100, 128, kt * 32 + kb, n1);
    }
    if (isA) {
#pragma unroll
        for (int kt = 0; kt < 4; ++kt) {
            Bf2[kt] = load_bfrag(Wf2, 64, 100, kt * 32 + kb, n2);
            Bz2[kt] = load_bfrag(Wz2, 64, 100, kt * 32 + kb, n2);
            Bh2[kt] = load_bfrag(Wh2, 64, 100, kt * 32 + kb, n2);
        }
    } else {
#pragma unroll
        for (int kt = 0; kt < 4; ++kt)
            Br2[kt] = load_bfrag(Wr2, 64, 100, kt * 32 + kb, n2);
    }

    const float b1f = (n1 < 100) ? bf1[n1] : 0.0f;
    const float b1z = (n1 < 100) ? bz1[n1] : 0.0f;
    const float b1r = (n1 < 100) ? br1[n1] : 0.0f;
    const float b1h = (n1 < 100) ? bh1[n1] : 0.0f;
    const float bF2 = isA ? bf2[n2] : 0.0f;
    const float bZ2 = isA ? bz2[n2] : 0.0f;
    const float bH2 = isA ? bh2[n2] : 0.0f;
    const float bR2 = isA ? 0.0f : br2[n2];

    // x staging (waves 4-7): thread -> (traj, 2 elems)
    const int t2  = tid & 255;
    const int xtr = t2 >> 5;
    const int xd  = (t2 & 31) * 2;

    const int col2 = n2 * 2;            // byte col for W2-output writes
    const int rb   = (lane >> 4) * 4;   // C/D row base

    f4v y_reg = splat(0.0f), yode = splat(0.0f), zf = splat(0.0f);
    float dt = tsv[1] - tsv[0];

    // ---- prologue: xbuf = x[1]; xparts for step 0 ----
    __syncthreads();
    if (!isA) {
        const float2 x1 = *(const float2*)
            &data[((size_t)(b0 + xtr) * TSTEP + 1) * 64 + xd];
        *(unsigned*)(smem + OFF_X + xtr * RB64 + (t2 & 31) * 4) = cvtpk(x1.x, x1.y);
    }
    __syncthreads();

    f4v xpz, xpr, xph;
    {
        const s8v x0 = load_af<RB64>(smem + OFF_X, lane, 0);
        const s8v x1 = load_af<RB64>(smem + OFF_X, lane, 1);
        xpz = mfma16(x1, Bz1[3], mfma16(x0, Bz1[2], splat(b1z)));
        xpr = mfma16(x1, Br1[3], mfma16(x0, Br1[2], splat(b1r)));
        xph = mfma16(x1, Bh1[3], mfma16(x0, Bh1[2], splat(b1h)));
    }

    for (int s = 0; s < TSTEP - 1; ++s) {
        // deferred out_ys store for step s-1 (write-ack drains under P1)
        if (isA && s > 0 && lane < 32) {
#pragma unroll
            for (int r = 0; r < 4; ++r)
                out_ys[((size_t)(b0 + rb + r) * (TSTEP - 1) + (s - 1)) * 64 + n2] =
                    y_reg[r];
        }
        // load x[s+2] (clamped) for NEXT step's xparts
        float2 xv;
        if (!isA) {
            const int sx = (s + 2 < TSTEP) ? (s + 2) : (TSTEP - 1);
            xv = *(const float2*)&data[((size_t)(b0 + xtr) * TSTEP + sx) * 64 + xd];
        }

        // ---- P1: f1 hidden (all waves, tile wv) ----
        {
            const s8v ya0 = load_af<RB64>(smem + OFF_Y, lane, 0);
            const s8v ya1 = load_af<RB64>(smem + OFF_Y, lane, 1);
            __builtin_amdgcn_s_setprio(1);
            f4v a = splat(b1f);
            a = mfma16(ya0, Bf1[0], a);
            a = mfma16(ya1, Bf1[1], a);
            __builtin_amdgcn_s_setprio(0);
            store_tanh(smem + OFF_HF, wv * 16, lane, a);
        }
        __syncthreads();

        // ---- P2: f2 out (w0-3) -> yode -> c; x[s+2] -> xbuf (w4-7) ----
        if (isA) {
            __builtin_amdgcn_s_setprio(1);
            f4v ac = splat(bF2);
#pragma unroll
            for (int kt = 0; kt < 4; ++kt)
                ac = mfma16(load_af<RB128>(smem + OFF_HF, lane, kt), Bf2[kt], ac);
            __builtin_amdgcn_s_setprio(0);
#pragma unroll
            for (int r = 0; r < 4; ++r) yode[r] = fmaf(dt, ac[r], y_reg[r]);
            store4(smem + OFF_C, col2, rb, RB64, yode[0], yode[1], yode[2], yode[3]);
        } else {
            *(unsigned*)(smem + OFF_X + xtr * RB64 + (t2 & 31) * 4) =
                cvtpk(xv.x, xv.y);
        }
        __syncthreads();

        // ---- P3: z1 + r1 hidden, K=64 from c, acc = xparts ----
        {
            const s8v c0 = load_af<RB64>(smem + OFF_C, lane, 0);
            const s8v c1 = load_af<RB64>(smem + OFF_C, lane, 1);
            __builtin_amdgcn_s_setprio(1);
            f4v az = mfma16(c1, Bz1[1], mfma16(c0, Bz1[0], xpz));
            f4v ar = mfma16(c1, Br1[1], mfma16(c0, Br1[0], xpr));
            __builtin_amdgcn_s_setprio(0);
            store_tanh(smem + OFF_HZ, wv * 16, lane, az);
            store_tanh(smem + OFF_HR, wv * 16, lane, ar);
        }
        __syncthreads();

        // ---- P4: z2 (w0-3, zf in regs) | r2 (w4-7) + ch=yode*r -> c ----
        if (isA) {
            __builtin_amdgcn_s_setprio(1);
            f4v az = splat(bZ2);
#pragma unroll
            for (int kt = 0; kt < 4; ++kt)
                az = mfma16(load_af<RB128>(smem + OFF_HZ, lane, kt), Bz2[kt], az);
            __builtin_amdgcn_s_setprio(0);
#pragma unroll
            for (int r = 0; r < 4; ++r) zf[r] = sigm_f(az[r]);
        } else {
            // hoist yode bf16 reads above the MFMA chain
            unsigned short yv[4];
#pragma unroll
            for (int r = 0; r < 4; ++r)
                yv[r] = *(const unsigned short*)
                    (smem + OFF_C + (rb + r) * RB64 + col2);
            __builtin_amdgcn_s_setprio(1);
            f4v ar = splat(bR2);
#pragma unroll
            for (int kt = 0; kt < 4; ++kt)
                ar = mfma16(load_af<RB128>(smem + OFF_HR, lane, kt), Br2[kt], ar);
            __builtin_amdgcn_s_setprio(0);
            float ch[4];
#pragma unroll
            for (int r = 0; r < 4; ++r)
                ch[r] = bf2f(yv[r]) * sigm_f(ar[r]);
            store4(smem + OFF_C, col2, rb, RB64, ch[0], ch[1], ch[2], ch[3]);
        }
        __syncthreads();

        // ---- P5: h1 hidden, K=64 from c(=ch), acc = xph ----
        {
            const s8v d0 = load_af<RB64>(smem + OFF_C, lane, 0);
            const s8v d1 = load_af<RB64>(smem + OFF_C, lane, 1);
            __builtin_amdgcn_s_setprio(1);
            f4v ah = mfma16(d1, Bh1[1], mfma16(d0, Bh1[0], xph));
            __builtin_amdgcn_s_setprio(0);
            store_tanh(smem + OFF_HH, wv * 16, lane, ah);
        }
        __syncthreads();

        // ---- P6: xp FIRST (independent), then h2 out (w0-3) + y update ----
        {   // next-step x-projections (xbuf holds x[s+2]); issue before h2
            const s8v x0 = load_af<RB64>(smem + OFF_X, lane, 0);
            const s8v x1 = load_af<RB64>(smem + OFF_X, lane, 1);
            __builtin_amdgcn_s_setprio(1);
            xpz = mfma16(x1, Bz1[3], mfma16(x0, Bz1[2], splat(b1z)));
            xpr = mfma16(x1, Br1[3], mfma16(x0, Br1[2], splat(b1r)));
            xph = mfma16(x1, Bh1[3], mfma16(x0, Bh1[2], splat(b1h)));
            __builtin_amdgcn_s_setprio(0);
        }
        if (isA) {
            __builtin_amdgcn_s_setprio(1);
            f4v ah = splat(bH2);
#pragma unroll
            for (int kt = 0; kt < 4; ++kt)
                ah = mfma16(load_af<RB128>(smem + OFF_HH, lane, kt), Bh2[kt], ah);
            __builtin_amdgcn_s_setprio(0);
#pragma unroll
            for (int r = 0; r < 4; ++r) {
                const float h = tanh_f(ah[r]);
                y_reg[r] = (1.0f - zf[r]) * h + zf[r] * yode[r];
            }
            store4(smem + OFF_Y, col2, rb, RB64, y_reg[0], y_reg[1], y_reg[2], y_reg[3]);
        }
        dt = tsv[s] - tsv[s + 1];
        __syncthreads();
    }

    // final flush: out_ys step 198 + out_yi
    if (isA && lane < 32) {
#pragma unroll
        for (int r = 0; r < 4; ++r) {
            out_ys[((size_t)(b0 + rb + r) * (TSTEP - 1) + (TSTEP - 2)) * 64 + n2] =
                y_reg[r];
            out_yi[(size_t)(b0 + rb + r) * 64 + n2] = y_reg[r];
        }
    }
}

extern "C" void kernel_launch(void* const* d_in, const int* in_sizes, int n_in,
                              void* d_out, int out_size, void* d_ws, size_t ws_size,
                              hipStream_t stream) {
    const float* data = (const float*)d_in[0];
    const float* tsv  = (const float*)d_in[1];
    const float* Wf1 = (const float*)d_in[2];  const float* bf1 = (const float*)d_in[3];
    const float* Wf2 = (const float*)d_in[4];  const float* bf2 = (const float*)d_in[5];
    const float* Wz1 = (const float*)d_in[6];  const float* bz1 = (const float*)d_in[7];
    const float* Wz2 = (const float*)d_in[8];  const float* bz2 = (const float*)d_in[9];
    const float* Wr1 = (const float*)d_in[10]; const float* br1 = (const float*)d_in[11];
    const float* Wr2 = (const float*)d_in[12]; const float* br2 = (const float*)d_in[13];
    const float* Wh1 = (const float*)d_in[14]; const float* bh1 = (const float*)d_in[15];
    const float* Wh2 = (const float*)d_in[16]; const float* bh2 = (const float*)d_in[17];

    float* out_yi = (float*)d_out;
    float* out_ys = out_yi + (size_t)NBT * 64;

    ode_rnn_r16<<<NBT / NT, 512, 0, stream>>>(
        data, tsv, Wf1, bf1, Wf2, bf2, Wz1, bz1, Wz2, bz2,
        Wr1, br1, Wr2, br2, Wh1, bh1, Wh2, bh2, out_yi, out_ys);
}